// Round 4
// baseline (177.907 us; speedup 1.0000x reference)
//
#include <hip/hip_runtime.h>

// MoE-LoRA top-1 dispatch.
// xpool: single pass over x -> (pool partials, xr_all for ALL experts, bf16 MFMA)
// router: reduce partials -> MLP -> top/balance ; out: xr_all[top[b]] @ B^T * 2
constexpr int B_ = 4, S_ = 2048, D_ = 4096, E_ = 4, R_ = 64, OUT_ = 4096;
constexpr int NMOD = 4, NREG = 3, HID_ = 128;
constexpr int RIN_ = D_ + NMOD + NREG;      // 4103
constexpr float SCALING_ = 2.0f;            // alpha/rank
constexpr int SB_  = 32;                    // xpool s-tile
constexpr int NSB_ = S_ / SB_;              // 64 s-blocks (= pool partial count)
constexpr int KC_  = 33;                    // router k-chunks of 128 (33*128 >= 4103)

// ws layout (float units) — everything fully written each call, no memset needed
constexpr size_t WS_PP    = 0;                                     // NSB_*B*D f32 partials
constexpr size_t WS_HACC2 = WS_PP + (size_t)NSB_ * B_ * D_;        // B*KC_*HID f32
constexpr size_t WS_TOP   = WS_HACC2 + B_ * KC_ * HID_;            // B ints
constexpr size_t WS_ABF   = WS_TOP + 16;                           // E*R*D bf16
constexpr size_t WS_BBF   = WS_ABF + (size_t)E_ * R_ * D_ / 2;     // E*OUT*R bf16
constexpr size_t WS_XR    = WS_BBF + (size_t)E_ * OUT_ * R_ / 2;   // E*B*S*R f32

using short8 = __attribute__((ext_vector_type(8))) short;
using f32x4  = __attribute__((ext_vector_type(4))) float;

__device__ inline unsigned short f2bf(float f) {  // RNE fp32 -> bf16
    unsigned u = __float_as_uint(f);
    unsigned r = u + 0x7FFFu + ((u >> 16) & 1u);
    return (unsigned short)(r >> 16);
}

__global__ void cvt_w_kernel(const float* __restrict__ A, const float* __restrict__ Bw,
                             ushort* __restrict__ Abf, ushort* __restrict__ Bbf) {
    int i = blockIdx.x * blockDim.x + threadIdx.x;  // float4 id
    constexpr int N4 = E_ * R_ * D_ / 4;            // 262144 per tensor
    if (i < N4) {
        float4 v = ((const float4*)A)[i];
        ((ushort4*)Abf)[i] = make_ushort4(f2bf(v.x), f2bf(v.y), f2bf(v.z), f2bf(v.w));
    } else {
        int j = i - N4;
        float4 v = ((const float4*)Bw)[j];
        ((ushort4*)Bbf)[j] = make_ushort4(f2bf(v.x), f2bf(v.y), f2bf(v.z), f2bf(v.w));
    }
}

// One pass over x: pool partials (f32 column sums over this block's 32 rows)
// + xr_all[e][b][s][r] for all 4 experts via bf16 MFMA.
// 4 waves: wave w -> experts {2*(w>>1), 2*(w>>1)+1}, m-half (w&1).
__global__ __launch_bounds__(256) void xpool_kernel(const float* __restrict__ x,
                                                    const ushort* __restrict__ Abf,
                                                    float* __restrict__ pool_part,
                                                    float* __restrict__ xr_all) {
    __shared__ ushort xs[SB_][72];       // 144B row stride (odd x16B) -> conflict-free b128
    __shared__ ushort as[E_][64][72];
    __shared__ float4 red[256];
    int b = blockIdx.y, sb = blockIdx.x;
    int s0 = sb * SB_;
    int t = threadIdx.x, lane = t & 63, w = t >> 6;
    int ep = w >> 1, mh = w & 1;
    const float* xb = x + ((size_t)b * S_ + s0) * D_;
    int xrow = t >> 4, xfq = t & 15;
    f32x4 acc[2][4] = {};
    for (int kc = 0; kc < D_ / 64; ++kc) {
        int k0 = kc * 64;
        // stage x 32x64 f32 -> bf16, accumulate pool partial in regs
        float4 v0 = *(const float4*)(xb + (size_t)xrow * D_ + k0 + xfq * 4);
        float4 v1 = *(const float4*)(xb + (size_t)(xrow + 16) * D_ + k0 + xfq * 4);
        *(ushort4*)&xs[xrow][xfq * 4]      = make_ushort4(f2bf(v0.x), f2bf(v0.y), f2bf(v0.z), f2bf(v0.w));
        *(ushort4*)&xs[xrow + 16][xfq * 4] = make_ushort4(f2bf(v1.x), f2bf(v1.y), f2bf(v1.z), f2bf(v1.w));
        red[t] = make_float4(v0.x + v1.x, v0.y + v1.y, v0.z + v1.z, v0.w + v1.w);
        // stage A chunk for all 4 experts: 4 x 64r x 64k bf16
#pragma unroll
        for (int j = 0; j < 8; ++j) {
            int lin = t + 256 * j;
            int e = lin >> 9, rr = (lin >> 3) & 63, cq = lin & 7;
            int4 av = *(const int4*)(Abf + ((size_t)e * R_ + rr) * D_ + k0 + cq * 8);
            *(int4*)&as[e][rr][cq * 8] = av;
        }
        __syncthreads();
        // pool column-reduce: thread f<16 sums the 16 partials of column-quad f
        if (t < 16) {
            float4 sum = red[t];
            for (int m = 1; m < 16; ++m) {
                float4 r = red[t + 16 * m];
                sum.x += r.x; sum.y += r.y; sum.z += r.z; sum.w += r.w;
            }
            *(float4*)&pool_part[(size_t)sb * (B_ * D_) + b * D_ + k0 + t * 4] = sum;
        }
        int mrow = mh * 16 + (lane & 15);
        int koff = (lane >> 4) * 8;
#pragma unroll
        for (int kk = 0; kk < 2; ++kk) {
            short8 af = *(const short8*)&xs[mrow][kk * 32 + koff];
#pragma unroll
            for (int ee = 0; ee < 2; ++ee) {
                int e = ep * 2 + ee;
#pragma unroll
                for (int n = 0; n < 4; ++n) {
                    short8 bf = *(const short8*)&as[e][n * 16 + (lane & 15)][kk * 32 + koff];
                    acc[ee][n] = __builtin_amdgcn_mfma_f32_16x16x32_bf16(af, bf, acc[ee][n], 0, 0, 0);
                }
            }
        }
        __syncthreads();   // protects xs/as/red reuse next iteration
    }
    // C/D: col = lane&15, row = (lane>>4)*4 + i
    int col0 = lane & 15;
    int rb   = mh * 16 + ((lane >> 4) << 2);
#pragma unroll
    for (int ee = 0; ee < 2; ++ee) {
        int e = ep * 2 + ee;
        float* xo = xr_all + (((size_t)e * B_ + b) * S_ + s0) * R_;
#pragma unroll
        for (int n = 0; n < 4; ++n)
#pragma unroll
            for (int i = 0; i < 4; ++i)
                xo[(size_t)(rb + i) * R_ + n * 16 + col0] = acc[ee][n][i];
    }
}

// hacc2[b][kc][h] = sum over chunk's 128 k-rows of router_in[k]*w1[k][h]
__global__ __launch_bounds__(256) void router_h_kernel(const float* __restrict__ pool_part,
                                                       const float* __restrict__ rel,
                                                       const float* __restrict__ reg,
                                                       const float* __restrict__ w1,
                                                       float* __restrict__ hacc2) {
    __shared__ float rin[128];
    __shared__ float red[256];
    int b = blockIdx.x, kc = blockIdx.y;
    int t = threadIdx.x;
    int k0 = kc * 128;
    if (t < 128) {
        int k = k0 + t;
        float v = 0.f;
        if (k < D_) {
            float s = 0.f;
            for (int p = 0; p < NSB_; ++p) s += pool_part[(size_t)p * (B_ * D_) + b * D_ + k];
            v = s * (1.0f / S_);
        } else if (k < D_ + NMOD) v = rel[b * NMOD + (k - D_)];
        else if (k < RIN_)        v = reg[b * NREG + (k - D_ - NMOD)];
        rin[t] = v;
    }
    __syncthreads();
    int h = t & 127, half = t >> 7;
    float acc = 0.f;
#pragma unroll 8
    for (int i = 0; i < 64; ++i) {
        int kk = 2 * i + half;
        int k = k0 + kk;
        if (k < RIN_) acc += rin[kk] * w1[(size_t)k * HID_ + h];
    }
    red[t] = acc;
    __syncthreads();
    if (t < 128)
        hacc2[((size_t)b * KC_ + kc) * HID_ + t] = red[t] + red[t + 128];
}

__global__ void router_finish_kernel(const float* __restrict__ hacc2, const float* __restrict__ b1,
                                     const float* __restrict__ w2, const float* __restrict__ b2,
                                     int* __restrict__ top, float* __restrict__ bal_out) {
    __shared__ float h_lds[B_][HID_];
    __shared__ float logit[B_][E_];
    __shared__ float probs[B_][E_];
    int t = threadIdx.x; // 128
    for (int b = 0; b < B_; ++b) {
        float v = b1[t];
        for (int j = 0; j < KC_; ++j) v += hacc2[((size_t)b * KC_ + j) * HID_ + t];
        float u = 0.7978845608028654f * (v + 0.044715f * v * v * v); // tanh-GELU
        h_lds[b][t] = 0.5f * v * (1.0f + tanhf(u));
    }
    __syncthreads();
    if (t < B_ * E_) {
        int b = t >> 2, e = t & 3;
        float acc = b2[e];
        for (int j = 0; j < HID_; ++j) acc += h_lds[b][j] * w2[j * E_ + e];
        logit[b][e] = acc;
    }
    __syncthreads();
    if (t < B_) {
        int b = t;
        float m = logit[b][0]; int arg = 0;
        for (int e = 1; e < E_; ++e) if (logit[b][e] > m) { m = logit[b][e]; arg = e; }
        float s = 0.f, p[E_];
        for (int e = 0; e < E_; ++e) { p[e] = expf(logit[b][e] - m); s += p[e]; }
        for (int e = 0; e < E_; ++e) probs[b][e] = p[e] / s;
        top[b] = arg;
    }
    __syncthreads();
    if (t == 0) {
        float bal = 0.f;
        for (int e = 0; e < E_; ++e) {
            float avg = 0.25f * (probs[0][e] + probs[1][e] + probs[2][e] + probs[3][e]);
            bal += avg * avg;
        }
        *bal_out = 0.01f * E_ * bal;
    }
}

// out[b,s,o] = 2 * sum_r xr_all[top[b]][b,s,r] * B_bf[e,o,r]
__global__ __launch_bounds__(256) void out_kernel(const float* __restrict__ xr_all,
                                                  const ushort* __restrict__ Bbf,
                                                  const int* __restrict__ top,
                                                  float* __restrict__ out) {
    __shared__ ushort xrs[64][72];
    __shared__ ushort bs[128][72];
    int b  = blockIdx.z;
    int e  = top[b];
    int s0 = blockIdx.x * 64, o0 = blockIdx.y * 128;
    int t = threadIdx.x, lane = t & 63, w = t >> 6;
    const float* xrb = xr_all + (((size_t)e * B_ + b) * S_) * R_;
#pragma unroll
    for (int i = 0; i < 4; ++i) {                   // stage xr 64x64 f32 -> bf16
        int lin = t + 256 * i; int row = lin >> 4, fq = lin & 15;
        float4 v = *(const float4*)(xrb + (size_t)(s0 + row) * R_ + fq * 4);
        *(ushort4*)&xrs[row][fq * 4] = make_ushort4(f2bf(v.x), f2bf(v.y), f2bf(v.z), f2bf(v.w));
    }
    const ushort* Bb = Bbf + (size_t)e * OUT_ * R_ + (size_t)o0 * R_;
#pragma unroll
    for (int i = 0; i < 4; ++i) {                   // stage B 128x64 bf16
        int lin = t + 256 * i; int row = lin >> 3, cq = lin & 7;
        int4 v = *(const int4*)(Bb + (size_t)row * R_ + cq * 8);
        *(int4*)&bs[row][cq * 8] = v;
    }
    __syncthreads();
    int mrow = w * 16 + (lane & 15);
    int koff = (lane >> 4) * 8;
    f32x4 acc[8] = {};
#pragma unroll
    for (int kk = 0; kk < 2; ++kk) {
        short8 af = *(const short8*)&xrs[mrow][kk * 32 + koff];
#pragma unroll
        for (int n = 0; n < 8; ++n) {
            short8 bf = *(const short8*)&bs[n * 16 + (lane & 15)][kk * 32 + koff];
            acc[n] = __builtin_amdgcn_mfma_f32_16x16x32_bf16(af, bf, acc[n], 0, 0, 0);
        }
    }
    int col0  = lane & 15;
    int rbase = (lane >> 4) << 2;
    float* ob = out + ((size_t)b * S_ + s0 + w * 16) * OUT_ + o0;
#pragma unroll
    for (int n = 0; n < 8; ++n)
#pragma unroll
        for (int i = 0; i < 4; ++i)
            ob[(size_t)(rbase + i) * OUT_ + n * 16 + col0] = acc[n][i] * SCALING_;
}

extern "C" void kernel_launch(void* const* d_in, const int* in_sizes, int n_in,
                              void* d_out, int out_size, void* d_ws, size_t ws_size,
                              hipStream_t stream) {
    const float* x   = (const float*)d_in[0];
    const float* rel = (const float*)d_in[1];
    const float* reg = (const float*)d_in[2];
    const float* lA  = (const float*)d_in[3];
    const float* lB  = (const float*)d_in[4];
    const float* w1  = (const float*)d_in[5];
    const float* b1  = (const float*)d_in[6];
    const float* w2  = (const float*)d_in[7];
    const float* b2  = (const float*)d_in[8];
    float* out = (float*)d_out;
    float* ws  = (float*)d_ws;

    float*  pp    = ws + WS_PP;
    float*  hacc2 = ws + WS_HACC2;
    int*    top   = (int*)(ws + WS_TOP);
    ushort* Abf   = (ushort*)(ws + WS_ABF);
    ushort* Bbf   = (ushort*)(ws + WS_BBF);
    float*  xr    = ws + WS_XR;

    cvt_w_kernel<<<2 * (E_ * R_ * D_ / 4) / 256, 256, 0, stream>>>(lA, lB, Abf, Bbf);
    xpool_kernel<<<dim3(NSB_, B_), 256, 0, stream>>>(x, Abf, pp, xr);
    router_h_kernel<<<dim3(B_, KC_), 256, 0, stream>>>(pp, rel, reg, w1, hacc2);
    router_finish_kernel<<<1, 128, 0, stream>>>(hacc2, b1, w2, b2, top,
                                                out + (size_t)out_size - 1);
    out_kernel<<<dim3(S_ / 64, OUT_ / 128, B_), 256, 0, stream>>>(xr, Bbf, top, out);
}

// Round 5
// 135.460 us; speedup vs baseline: 1.3134x; 1.3134x over previous
//
#include <hip/hip_runtime.h>

// MoE-LoRA top-1 dispatch.
// xpool (K-split x4): single pass over x -> pool partials + xr_all partials (all experts, bf16 MFMA)
// xr_red: sum K-partials -> bf16 xr ; router: partial-sum -> MLP -> top/balance ; out: xr@B^T*2
constexpr int B_ = 4, S_ = 2048, D_ = 4096, E_ = 4, R_ = 64, OUT_ = 4096;
constexpr int NMOD = 4, NREG = 3, HID_ = 128;
constexpr int RIN_ = D_ + NMOD + NREG;      // 4103
constexpr float SCALING_ = 2.0f;            // alpha/rank
constexpr int SB_  = 64;                    // xpool s-tile
constexpr int NSB_ = S_ / SB_;              // 32 s-blocks (= pool partial count)
constexpr int KQ_  = 4;                     // K-split chunks of 1024
constexpr int KCH_ = D_ / KQ_;              // 1024
constexpr int KC_  = 33;                    // router k-chunks of 128 (33*128 >= 4103)
constexpr size_t XRN_ = (size_t)E_ * B_ * S_ * R_;  // 2097152

// ws layout (float units) — everything fully written each call, no memset needed
constexpr size_t WS_PP    = 0;                                     // NSB_*B*D f32 pool partials
constexpr size_t WS_HACC2 = WS_PP + (size_t)NSB_ * B_ * D_;        // B*KC_*HID f32
constexpr size_t WS_TOP   = WS_HACC2 + B_ * KC_ * HID_;            // B ints
constexpr size_t WS_ABF   = WS_TOP + 16;                           // E*R*D bf16
constexpr size_t WS_BBF   = WS_ABF + (size_t)E_ * R_ * D_ / 2;     // E*OUT*R bf16
constexpr size_t WS_XRP   = WS_BBF + (size_t)E_ * OUT_ * R_ / 2;   // KQ_*E*B*S*R f32 partials
constexpr size_t WS_XRB   = WS_XRP + KQ_ * XRN_;                   // E*B*S*R bf16

using short8 = __attribute__((ext_vector_type(8))) short;
using f32x4  = __attribute__((ext_vector_type(4))) float;

__device__ inline unsigned short f2bf(float f) {  // RNE fp32 -> bf16
    unsigned u = __float_as_uint(f);
    unsigned r = u + 0x7FFFu + ((u >> 16) & 1u);
    return (unsigned short)(r >> 16);
}

__global__ void cvt_w_kernel(const float* __restrict__ A, const float* __restrict__ Bw,
                             ushort* __restrict__ Abf, ushort* __restrict__ Bbf) {
    int i = blockIdx.x * blockDim.x + threadIdx.x;  // float4 id
    constexpr int N4 = E_ * R_ * D_ / 4;            // 262144 per tensor
    if (i < N4) {
        float4 v = ((const float4*)A)[i];
        ((ushort4*)Abf)[i] = make_ushort4(f2bf(v.x), f2bf(v.y), f2bf(v.z), f2bf(v.w));
    } else {
        int j = i - N4;
        float4 v = ((const float4*)Bw)[j];
        ((ushort4*)Bbf)[j] = make_ushort4(f2bf(v.x), f2bf(v.y), f2bf(v.z), f2bf(v.w));
    }
}

// One pass over x (this block's 64 rows x 1024 K-cols):
//   pool partials (f32 column sums) + xr partials for ALL 4 experts (bf16 MFMA).
// Wave w owns m-tile rows [w*16, w*16+16); all 16 n-tiles (4 experts x 4).
__global__ __launch_bounds__(256, 3) void xpool_kernel(const float* __restrict__ x,
                                                       const ushort* __restrict__ Abf,
                                                       float* __restrict__ pool_part,
                                                       float* __restrict__ xr_part) {
    __shared__ ushort xs[SB_][72];       // 144B row stride (odd x16B) -> conflict-free b128
    __shared__ ushort as[E_][64][72];
    __shared__ float4 red2[4][16];
    int b = blockIdx.y, sb = blockIdx.x, kq = blockIdx.z;
    int s0 = sb * SB_;
    int t = threadIdx.x, lane = t & 63, w = t >> 6;
    const float* xb = x + ((size_t)b * S_ + s0) * D_;
    int xrow = t >> 4, xfq = t & 15;
    f32x4 acc[E_][4] = {};
    for (int kc = 0; kc < KCH_ / 64; ++kc) {
        int k0 = kq * KCH_ + kc * 64;
        // stage x 64x64 f32 -> bf16; per-thread pool partial of its 4 rows
        float4 v0 = *(const float4*)(xb + (size_t)xrow * D_ + k0 + xfq * 4);
        float4 v1 = *(const float4*)(xb + (size_t)(xrow + 16) * D_ + k0 + xfq * 4);
        float4 v2 = *(const float4*)(xb + (size_t)(xrow + 32) * D_ + k0 + xfq * 4);
        float4 v3 = *(const float4*)(xb + (size_t)(xrow + 48) * D_ + k0 + xfq * 4);
        *(ushort4*)&xs[xrow][xfq * 4]      = make_ushort4(f2bf(v0.x), f2bf(v0.y), f2bf(v0.z), f2bf(v0.w));
        *(ushort4*)&xs[xrow + 16][xfq * 4] = make_ushort4(f2bf(v1.x), f2bf(v1.y), f2bf(v1.z), f2bf(v1.w));
        *(ushort4*)&xs[xrow + 32][xfq * 4] = make_ushort4(f2bf(v2.x), f2bf(v2.y), f2bf(v2.z), f2bf(v2.w));
        *(ushort4*)&xs[xrow + 48][xfq * 4] = make_ushort4(f2bf(v3.x), f2bf(v3.y), f2bf(v3.z), f2bf(v3.w));
        float4 v = make_float4(v0.x + v1.x + v2.x + v3.x, v0.y + v1.y + v2.y + v3.y,
                               v0.z + v1.z + v2.z + v3.z, v0.w + v1.w + v2.w + v3.w);
        // stage A chunk for all 4 experts: 4 x 64r x 64k bf16
#pragma unroll
        for (int j = 0; j < 8; ++j) {
            int lin = t + 256 * j;
            int e = lin >> 9, rr = (lin >> 3) & 63, cq = lin & 7;
            int4 av = *(const int4*)(Abf + ((size_t)e * R_ + rr) * D_ + k0 + cq * 8);
            *(int4*)&as[e][rr][cq * 8] = av;
        }
        // wave-level xor reduce over the wave's 4 row-groups (lane bits 4,5)
        v.x += __shfl_xor(v.x, 16); v.y += __shfl_xor(v.y, 16);
        v.z += __shfl_xor(v.z, 16); v.w += __shfl_xor(v.w, 16);
        v.x += __shfl_xor(v.x, 32); v.y += __shfl_xor(v.y, 32);
        v.z += __shfl_xor(v.z, 32); v.w += __shfl_xor(v.w, 32);
        if (lane < 16) red2[w][lane] = v;
        __syncthreads();
        // cross-wave pool finish: 16 threads own one column-quad each
        if (t < 16) {
            float4 s = red2[0][t], r1 = red2[1][t], r2 = red2[2][t], r3 = red2[3][t];
            s.x += r1.x + r2.x + r3.x; s.y += r1.y + r2.y + r3.y;
            s.z += r1.z + r2.z + r3.z; s.w += r1.w + r2.w + r3.w;
            *(float4*)&pool_part[(size_t)sb * (B_ * D_) + b * D_ + k0 + t * 4] = s;
        }
        int mrow = w * 16 + (lane & 15);
        int koff = (lane >> 4) * 8;
#pragma unroll
        for (int kk = 0; kk < 2; ++kk) {
            short8 af = *(const short8*)&xs[mrow][kk * 32 + koff];
#pragma unroll
            for (int e = 0; e < E_; ++e)
#pragma unroll
                for (int n = 0; n < 4; ++n) {
                    short8 bf = *(const short8*)&as[e][n * 16 + (lane & 15)][kk * 32 + koff];
                    acc[e][n] = __builtin_amdgcn_mfma_f32_16x16x32_bf16(af, bf, acc[e][n], 0, 0, 0);
                }
        }
        __syncthreads();   // protects xs/as/red2 reuse next iteration
    }
    // C/D: col = lane&15, row = (lane>>4)*4 + i  (within wave's m-tile)
    int col0 = lane & 15;
    int rb   = w * 16 + ((lane >> 4) << 2);
#pragma unroll
    for (int e = 0; e < E_; ++e) {
        float* xo = xr_part + (size_t)kq * (E_ * B_ * S_ * R_) +
                    (((size_t)e * B_ + b) * S_ + s0) * R_;
#pragma unroll
        for (int n = 0; n < 4; ++n)
#pragma unroll
            for (int i = 0; i < 4; ++i)
                xo[(size_t)(rb + i) * R_ + n * 16 + col0] = acc[e][n][i];
    }
}

// xr_bf = bf16( sum_kq xr_part[kq] )
__global__ __launch_bounds__(256) void xr_red_kernel(const float* __restrict__ xr_part,
                                                     ushort* __restrict__ xr_bf) {
    size_t i = (size_t)blockIdx.x * 256 + threadIdx.x;   // float4 id, XRN_/4 total
    constexpr size_t STR = XRN_ / 4;
    float4 s = ((const float4*)xr_part)[i];
    float4 a = ((const float4*)xr_part)[i + STR];
    float4 c = ((const float4*)xr_part)[i + 2 * STR];
    float4 d = ((const float4*)xr_part)[i + 3 * STR];
    s.x += a.x + c.x + d.x; s.y += a.y + c.y + d.y;
    s.z += a.z + c.z + d.z; s.w += a.w + c.w + d.w;
    ((ushort4*)xr_bf)[i] = make_ushort4(f2bf(s.x), f2bf(s.y), f2bf(s.z), f2bf(s.w));
}

// hacc2[b][kc][h] = sum over chunk's 128 k-rows of router_in[k]*w1[k][h]
__global__ __launch_bounds__(256) void router_h_kernel(const float* __restrict__ pool_part,
                                                       const float* __restrict__ rel,
                                                       const float* __restrict__ reg,
                                                       const float* __restrict__ w1,
                                                       float* __restrict__ hacc2) {
    __shared__ float rin[128];
    __shared__ float red[256];
    int b = blockIdx.x, kc = blockIdx.y;
    int t = threadIdx.x;
    int k0 = kc * 128;
    if (t < 128) {
        int k = k0 + t;
        float v = 0.f;
        if (k < D_) {
            float s = 0.f;
            for (int p = 0; p < NSB_; ++p) s += pool_part[(size_t)p * (B_ * D_) + b * D_ + k];
            v = s * (1.0f / S_);
        } else if (k < D_ + NMOD) v = rel[b * NMOD + (k - D_)];
        else if (k < RIN_)        v = reg[b * NREG + (k - D_ - NMOD)];
        rin[t] = v;
    }
    __syncthreads();
    int h = t & 127, half = t >> 7;
    float acc = 0.f;
#pragma unroll 8
    for (int i = 0; i < 64; ++i) {
        int kk = 2 * i + half;
        int k = k0 + kk;
        if (k < RIN_) acc += rin[kk] * w1[(size_t)k * HID_ + h];
    }
    red[t] = acc;
    __syncthreads();
    if (t < 128)
        hacc2[((size_t)b * KC_ + kc) * HID_ + t] = red[t] + red[t + 128];
}

__global__ void router_finish_kernel(const float* __restrict__ hacc2, const float* __restrict__ b1,
                                     const float* __restrict__ w2, const float* __restrict__ b2,
                                     int* __restrict__ top, float* __restrict__ bal_out) {
    __shared__ float h_lds[B_][HID_];
    __shared__ float logit[B_][E_];
    __shared__ float probs[B_][E_];
    int t = threadIdx.x; // 128
    for (int b = 0; b < B_; ++b) {
        float v = b1[t];
        for (int j = 0; j < KC_; ++j) v += hacc2[((size_t)b * KC_ + j) * HID_ + t];
        float u = 0.7978845608028654f * (v + 0.044715f * v * v * v); // tanh-GELU
        h_lds[b][t] = 0.5f * v * (1.0f + tanhf(u));
    }
    __syncthreads();
    if (t < B_ * E_) {
        int b = t >> 2, e = t & 3;
        float acc = b2[e];
        for (int j = 0; j < HID_; ++j) acc += h_lds[b][j] * w2[j * E_ + e];
        logit[b][e] = acc;
    }
    __syncthreads();
    if (t < B_) {
        int b = t;
        float m = logit[b][0]; int arg = 0;
        for (int e = 1; e < E_; ++e) if (logit[b][e] > m) { m = logit[b][e]; arg = e; }
        float s = 0.f, p[E_];
        for (int e = 0; e < E_; ++e) { p[e] = expf(logit[b][e] - m); s += p[e]; }
        for (int e = 0; e < E_; ++e) probs[b][e] = p[e] / s;
        top[b] = arg;
    }
    __syncthreads();
    if (t == 0) {
        float bal = 0.f;
        for (int e = 0; e < E_; ++e) {
            float avg = 0.25f * (probs[0][e] + probs[1][e] + probs[2][e] + probs[3][e]);
            bal += avg * avg;
        }
        *bal_out = 0.01f * E_ * bal;
    }
}

// out[b,s,o] = 2 * sum_r xr_bf[top[b]][b,s,r] * B_bf[e,o,r]
__global__ __launch_bounds__(256) void out_kernel(const ushort* __restrict__ xr_bf,
                                                  const ushort* __restrict__ Bbf,
                                                  const int* __restrict__ top,
                                                  float* __restrict__ out) {
    __shared__ ushort xrs[64][72];
    __shared__ ushort bs[128][72];
    int b  = blockIdx.z;
    int e  = top[b];
    int s0 = blockIdx.x * 64, o0 = blockIdx.y * 128;
    int t = threadIdx.x, lane = t & 63, w = t >> 6;
    const ushort* xrb = xr_bf + (((size_t)e * B_ + b) * S_ + s0) * R_;
#pragma unroll
    for (int i = 0; i < 2; ++i) {                   // stage xr 64x64 bf16
        int lin = t + 256 * i; int row = lin >> 3, cq = lin & 7;
        int4 v = *(const int4*)(xrb + (size_t)row * R_ + cq * 8);
        *(int4*)&xrs[row][cq * 8] = v;
    }
    const ushort* Bb = Bbf + (size_t)e * OUT_ * R_ + (size_t)o0 * R_;
#pragma unroll
    for (int i = 0; i < 4; ++i) {                   // stage B 128x64 bf16
        int lin = t + 256 * i; int row = lin >> 3, cq = lin & 7;
        int4 v = *(const int4*)(Bb + (size_t)row * R_ + cq * 8);
        *(int4*)&bs[row][cq * 8] = v;
    }
    __syncthreads();
    int mrow = w * 16 + (lane & 15);
    int koff = (lane >> 4) * 8;
    f32x4 acc[8] = {};
#pragma unroll
    for (int kk = 0; kk < 2; ++kk) {
        short8 af = *(const short8*)&xrs[mrow][kk * 32 + koff];
#pragma unroll
        for (int n = 0; n < 8; ++n) {
            short8 bf = *(const short8*)&bs[n * 16 + (lane & 15)][kk * 32 + koff];
            acc[n] = __builtin_amdgcn_mfma_f32_16x16x32_bf16(af, bf, acc[n], 0, 0, 0);
        }
    }
    int col0  = lane & 15;
    int rbase = (lane >> 4) << 2;
    float* ob = out + ((size_t)b * S_ + s0 + w * 16) * OUT_ + o0;
#pragma unroll
    for (int n = 0; n < 8; ++n)
#pragma unroll
        for (int i = 0; i < 4; ++i)
            ob[(size_t)(rbase + i) * OUT_ + n * 16 + col0] = acc[n][i] * SCALING_;
}

extern "C" void kernel_launch(void* const* d_in, const int* in_sizes, int n_in,
                              void* d_out, int out_size, void* d_ws, size_t ws_size,
                              hipStream_t stream) {
    const float* x   = (const float*)d_in[0];
    const float* rel = (const float*)d_in[1];
    const float* reg = (const float*)d_in[2];
    const float* lA  = (const float*)d_in[3];
    const float* lB  = (const float*)d_in[4];
    const float* w1  = (const float*)d_in[5];
    const float* b1  = (const float*)d_in[6];
    const float* w2  = (const float*)d_in[7];
    const float* b2  = (const float*)d_in[8];
    float* out = (float*)d_out;
    float* ws  = (float*)d_ws;

    float*  pp    = ws + WS_PP;
    float*  hacc2 = ws + WS_HACC2;
    int*    top   = (int*)(ws + WS_TOP);
    ushort* Abf   = (ushort*)(ws + WS_ABF);
    ushort* Bbf   = (ushort*)(ws + WS_BBF);
    float*  xrp   = ws + WS_XRP;
    ushort* xrb   = (ushort*)(ws + WS_XRB);

    cvt_w_kernel<<<2 * (E_ * R_ * D_ / 4) / 256, 256, 0, stream>>>(lA, lB, Abf, Bbf);
    xpool_kernel<<<dim3(NSB_, B_, KQ_), 256, 0, stream>>>(x, Abf, pp, xrp);
    xr_red_kernel<<<(int)(XRN_ / 4 / 256), 256, 0, stream>>>(xrp, xrb);
    router_h_kernel<<<dim3(B_, KC_), 256, 0, stream>>>(pp, rel, reg, w1, hacc2);
    router_finish_kernel<<<1, 128, 0, stream>>>(hacc2, b1, w2, b2, top,
                                                out + (size_t)out_size - 1);
    out_kernel<<<dim3(S_ / 64, OUT_ / 128, B_), 256, 0, stream>>>(xrb, Bbf, top, out);
}

// Round 6
// 133.309 us; speedup vs baseline: 1.3345x; 1.0161x over previous
//
#include <hip/hip_runtime.h>

// MoE-LoRA top-1 dispatch.
// xe (expert-split): one pass over x per expert-block -> pool partials (e==0) + bf16 xr_all
// router: partial-sum -> MLP -> top/balance ; out: xr[top[b]] @ B^T * 2
constexpr int B_ = 4, S_ = 2048, D_ = 4096, E_ = 4, R_ = 64, OUT_ = 4096;
constexpr int NMOD = 4, NREG = 3, HID_ = 128;
constexpr int RIN_ = D_ + NMOD + NREG;      // 4103
constexpr float SCALING_ = 2.0f;            // alpha/rank
constexpr int SB_  = 64;                    // xe s-tile
constexpr int NSB_ = S_ / SB_;              // 32 s-blocks (= pool partial count)
constexpr int KC_  = 33;                    // router k-chunks of 128 (33*128 >= 4103)

// ws layout (float units) — everything fully written each call, no memset needed
constexpr size_t WS_PP    = 0;                                     // NSB_*B*D f32 pool partials
constexpr size_t WS_HACC2 = WS_PP + (size_t)NSB_ * B_ * D_;        // B*KC_*HID f32
constexpr size_t WS_TOP   = WS_HACC2 + B_ * KC_ * HID_;            // B ints
constexpr size_t WS_ABF   = WS_TOP + 16;                           // E*R*D bf16
constexpr size_t WS_BBF   = WS_ABF + (size_t)E_ * R_ * D_ / 2;     // E*OUT*R bf16
constexpr size_t WS_XRB   = WS_BBF + (size_t)E_ * OUT_ * R_ / 2;   // E*B*S*R bf16

using short8 = __attribute__((ext_vector_type(8))) short;
using f32x4  = __attribute__((ext_vector_type(4))) float;

__device__ inline unsigned short f2bf(float f) {  // RNE fp32 -> bf16
    unsigned u = __float_as_uint(f);
    unsigned r = u + 0x7FFFu + ((u >> 16) & 1u);
    return (unsigned short)(r >> 16);
}

__global__ void cvt_w_kernel(const float* __restrict__ A, const float* __restrict__ Bw,
                             ushort* __restrict__ Abf, ushort* __restrict__ Bbf) {
    int i = blockIdx.x * blockDim.x + threadIdx.x;  // float4 id
    constexpr int N4 = E_ * R_ * D_ / 4;            // 262144 per tensor
    if (i < N4) {
        float4 v = ((const float4*)A)[i];
        ((ushort4*)Abf)[i] = make_ushort4(f2bf(v.x), f2bf(v.y), f2bf(v.z), f2bf(v.w));
    } else {
        int j = i - N4;
        float4 v = ((const float4*)Bw)[j];
        ((ushort4*)Bbf)[j] = make_ushort4(f2bf(v.x), f2bf(v.y), f2bf(v.z), f2bf(v.w));
    }
}

// Block = (sb, b, e): 64 s-rows x full D for ONE expert; 8 waves.
// Wave w: m-tile m=w&3 (16 rows), n-pair p=w>>2 (two 16-col n-tiles).
// Pipelined: global loads for kc+1 issued before MFMA of kc.
__global__ __launch_bounds__(512, 4) void xe_kernel(const float* __restrict__ x,
                                                    const ushort* __restrict__ Abf,
                                                    float* __restrict__ pool_part,
                                                    ushort* __restrict__ xr_bf) {
    __shared__ ushort xs[SB_][72];      // 144B row stride (odd x16B)
    __shared__ ushort as[R_][72];
    __shared__ float4 red2[8][16];
    int sb = blockIdx.x, b = blockIdx.y, e = blockIdx.z;
    int s0 = sb * SB_;
    int t = threadIdx.x, lane = t & 63, w = t >> 6;
    int m = w & 3, p = w >> 2;
    const float*  xb = x   + ((size_t)b * S_ + s0) * D_;
    const ushort* Ab = Abf + (size_t)e * R_ * D_;
    int xrow = t >> 4, xfq = t & 15;    // x rows xrow, xrow+32 ; col quad xfq
    int arow = t >> 3, acq = t & 7;     // A row arow ; col oct acq
    // prologue: load kc=0
    float4 v0 = *(const float4*)(xb + (size_t)xrow * D_ + xfq * 4);
    float4 v1 = *(const float4*)(xb + (size_t)(xrow + 32) * D_ + xfq * 4);
    int4  av  = *(const int4*)(Ab + (size_t)arow * D_ + acq * 8);
    f32x4 acc[2] = {};
    int mrow = m * 16 + (lane & 15);
    int koff = (lane >> 4) * 8;
    for (int kc = 0; kc < D_ / 64; ++kc) {
        __syncthreads();   // consumers of previous tile done
        *(ushort4*)&xs[xrow][xfq * 4]      = make_ushort4(f2bf(v0.x), f2bf(v0.y), f2bf(v0.z), f2bf(v0.w));
        *(ushort4*)&xs[xrow + 32][xfq * 4] = make_ushort4(f2bf(v1.x), f2bf(v1.y), f2bf(v1.z), f2bf(v1.w));
        *(int4*)&as[arow][acq * 8] = av;
        if (e == 0) {      // block-uniform: pool partial only once per (sb,b)
            float4 v = make_float4(v0.x + v1.x, v0.y + v1.y, v0.z + v1.z, v0.w + v1.w);
            v.x += __shfl_xor(v.x, 16); v.y += __shfl_xor(v.y, 16);
            v.z += __shfl_xor(v.z, 16); v.w += __shfl_xor(v.w, 16);
            v.x += __shfl_xor(v.x, 32); v.y += __shfl_xor(v.y, 32);
            v.z += __shfl_xor(v.z, 32); v.w += __shfl_xor(v.w, 32);
            if (lane < 16) red2[w][lane] = v;
        }
        __syncthreads();   // tile + red2 ready
        if (e == 0 && t < 16) {
            float4 s = red2[0][t];
#pragma unroll
            for (int j = 1; j < 8; ++j) {
                float4 r = red2[j][t];
                s.x += r.x; s.y += r.y; s.z += r.z; s.w += r.w;
            }
            *(float4*)&pool_part[(size_t)sb * (B_ * D_) + b * D_ + kc * 64 + t * 4] = s;
        }
        if (kc < D_ / 64 - 1) {        // issue next-tile loads; in flight across MFMA
            int k0n = (kc + 1) * 64;
            v0 = *(const float4*)(xb + (size_t)xrow * D_ + k0n + xfq * 4);
            v1 = *(const float4*)(xb + (size_t)(xrow + 32) * D_ + k0n + xfq * 4);
            av = *(const int4*)(Ab + (size_t)arow * D_ + k0n + acq * 8);
        }
#pragma unroll
        for (int kk = 0; kk < 2; ++kk) {
            short8 af = *(const short8*)&xs[mrow][kk * 32 + koff];
#pragma unroll
            for (int n = 0; n < 2; ++n) {
                short8 bf = *(const short8*)&as[(p * 2 + n) * 16 + (lane & 15)][kk * 32 + koff];
                acc[n] = __builtin_amdgcn_mfma_f32_16x16x32_bf16(af, bf, acc[n], 0, 0, 0);
            }
        }
    }
    // C/D: col = lane&15, row = (lane>>4)*4 + i ; write bf16 xr directly
    int col0 = lane & 15;
    int rb   = m * 16 + ((lane >> 4) << 2);
    ushort* xo = xr_bf + (((size_t)e * B_ + b) * S_ + s0) * R_;
#pragma unroll
    for (int n = 0; n < 2; ++n)
#pragma unroll
        for (int i = 0; i < 4; ++i)
            xo[(size_t)(rb + i) * R_ + (p * 2 + n) * 16 + col0] = f2bf(acc[n][i]);
}

// hacc2[b][kc][h] = sum over chunk's 128 k-rows of router_in[k]*w1[k][h]
__global__ __launch_bounds__(256) void router_h_kernel(const float* __restrict__ pool_part,
                                                       const float* __restrict__ rel,
                                                       const float* __restrict__ reg,
                                                       const float* __restrict__ w1,
                                                       float* __restrict__ hacc2) {
    __shared__ float rin[128];
    __shared__ float red[256];
    int b = blockIdx.x, kc = blockIdx.y;
    int t = threadIdx.x;
    int k0 = kc * 128;
    if (t < 128) {
        int k = k0 + t;
        float v = 0.f;
        if (k < D_) {
            float s = 0.f;
            for (int p = 0; p < NSB_; ++p) s += pool_part[(size_t)p * (B_ * D_) + b * D_ + k];
            v = s * (1.0f / S_);
        } else if (k < D_ + NMOD) v = rel[b * NMOD + (k - D_)];
        else if (k < RIN_)        v = reg[b * NREG + (k - D_ - NMOD)];
        rin[t] = v;
    }
    __syncthreads();
    int h = t & 127, half = t >> 7;
    float acc = 0.f;
#pragma unroll 8
    for (int i = 0; i < 64; ++i) {
        int kk = 2 * i + half;
        int k = k0 + kk;
        if (k < RIN_) acc += rin[kk] * w1[(size_t)k * HID_ + h];
    }
    red[t] = acc;
    __syncthreads();
    if (t < 128)
        hacc2[((size_t)b * KC_ + kc) * HID_ + t] = red[t] + red[t + 128];
}

__global__ void router_finish_kernel(const float* __restrict__ hacc2, const float* __restrict__ b1,
                                     const float* __restrict__ w2, const float* __restrict__ b2,
                                     int* __restrict__ top, float* __restrict__ bal_out) {
    __shared__ float h_lds[B_][HID_];
    __shared__ float logit[B_][E_];
    __shared__ float probs[B_][E_];
    int t = threadIdx.x; // 128
    for (int b = 0; b < B_; ++b) {
        float v = b1[t];
        for (int j = 0; j < KC_; ++j) v += hacc2[((size_t)b * KC_ + j) * HID_ + t];
        float u = 0.7978845608028654f * (v + 0.044715f * v * v * v); // tanh-GELU
        h_lds[b][t] = 0.5f * v * (1.0f + tanhf(u));
    }
    __syncthreads();
    if (t < B_ * E_) {
        int b = t >> 2, e = t & 3;
        float acc = b2[e];
        for (int j = 0; j < HID_; ++j) acc += h_lds[b][j] * w2[j * E_ + e];
        logit[b][e] = acc;
    }
    __syncthreads();
    if (t < B_) {
        int b = t;
        float m = logit[b][0]; int arg = 0;
        for (int e = 1; e < E_; ++e) if (logit[b][e] > m) { m = logit[b][e]; arg = e; }
        float s = 0.f, p[E_];
        for (int e = 0; e < E_; ++e) { p[e] = expf(logit[b][e] - m); s += p[e]; }
        for (int e = 0; e < E_; ++e) probs[b][e] = p[e] / s;
        top[b] = arg;
    }
    __syncthreads();
    if (t == 0) {
        float bal = 0.f;
        for (int e = 0; e < E_; ++e) {
            float avg = 0.25f * (probs[0][e] + probs[1][e] + probs[2][e] + probs[3][e]);
            bal += avg * avg;
        }
        *bal_out = 0.01f * E_ * bal;
    }
}

// out[b,s,o] = 2 * sum_r xr_bf[top[b]][b,s,r] * B_bf[e,o,r]
__global__ __launch_bounds__(256) void out_kernel(const ushort* __restrict__ xr_bf,
                                                  const ushort* __restrict__ Bbf,
                                                  const int* __restrict__ top,
                                                  float* __restrict__ out) {
    __shared__ ushort xrs[64][72];
    __shared__ ushort bs[128][72];
    int b  = blockIdx.z;
    int e  = top[b];
    int s0 = blockIdx.x * 64, o0 = blockIdx.y * 128;
    int t = threadIdx.x, lane = t & 63, w = t >> 6;
    const ushort* xrb = xr_bf + (((size_t)e * B_ + b) * S_ + s0) * R_;
#pragma unroll
    for (int i = 0; i < 2; ++i) {                   // stage xr 64x64 bf16
        int lin = t + 256 * i; int row = lin >> 3, cq = lin & 7;
        int4 v = *(const int4*)(xrb + (size_t)row * R_ + cq * 8);
        *(int4*)&xrs[row][cq * 8] = v;
    }
    const ushort* Bb = Bbf + (size_t)e * OUT_ * R_ + (size_t)o0 * R_;
#pragma unroll
    for (int i = 0; i < 4; ++i) {                   // stage B 128x64 bf16
        int lin = t + 256 * i; int row = lin >> 3, cq = lin & 7;
        int4 v = *(const int4*)(Bb + (size_t)row * R_ + cq * 8);
        *(int4*)&bs[row][cq * 8] = v;
    }
    __syncthreads();
    int mrow = w * 16 + (lane & 15);
    int koff = (lane >> 4) * 8;
    f32x4 acc[8] = {};
#pragma unroll
    for (int kk = 0; kk < 2; ++kk) {
        short8 af = *(const short8*)&xrs[mrow][kk * 32 + koff];
#pragma unroll
        for (int n = 0; n < 8; ++n) {
            short8 bf = *(const short8*)&bs[n * 16 + (lane & 15)][kk * 32 + koff];
            acc[n] = __builtin_amdgcn_mfma_f32_16x16x32_bf16(af, bf, acc[n], 0, 0, 0);
        }
    }
    int col0  = lane & 15;
    int rbase = (lane >> 4) << 2;
    float* ob = out + ((size_t)b * S_ + s0 + w * 16) * OUT_ + o0;
#pragma unroll
    for (int n = 0; n < 8; ++n)
#pragma unroll
        for (int i = 0; i < 4; ++i)
            ob[(size_t)(rbase + i) * OUT_ + n * 16 + col0] = acc[n][i] * SCALING_;
}

extern "C" void kernel_launch(void* const* d_in, const int* in_sizes, int n_in,
                              void* d_out, int out_size, void* d_ws, size_t ws_size,
                              hipStream_t stream) {
    const float* x   = (const float*)d_in[0];
    const float* rel = (const float*)d_in[1];
    const float* reg = (const float*)d_in[2];
    const float* lA  = (const float*)d_in[3];
    const float* lB  = (const float*)d_in[4];
    const float* w1  = (const float*)d_in[5];
    const float* b1  = (const float*)d_in[6];
    const float* w2  = (const float*)d_in[7];
    const float* b2  = (const float*)d_in[8];
    float* out = (float*)d_out;
    float* ws  = (float*)d_ws;

    float*  pp    = ws + WS_PP;
    float*  hacc2 = ws + WS_HACC2;
    int*    top   = (int*)(ws + WS_TOP);
    ushort* Abf   = (ushort*)(ws + WS_ABF);
    ushort* Bbf   = (ushort*)(ws + WS_BBF);
    ushort* xrb   = (ushort*)(ws + WS_XRB);

    cvt_w_kernel<<<2 * (E_ * R_ * D_ / 4) / 256, 256, 0, stream>>>(lA, lB, Abf, Bbf);
    xe_kernel<<<dim3(NSB_, B_, E_), 512, 0, stream>>>(x, Abf, pp, xrb);
    router_h_kernel<<<dim3(B_, KC_), 256, 0, stream>>>(pp, rel, reg, w1, hacc2);
    router_finish_kernel<<<1, 128, 0, stream>>>(hacc2, b1, w2, b2, top,
                                                out + (size_t)out_size - 1);
    out_kernel<<<dim3(S_ / 64, OUT_ / 128, B_), 256, 0, stream>>>(xrb, Bbf, top, out);
}